// Round 1
// baseline (8432.883 us; speedup 1.0000x reference)
//
#include <hip/hip_runtime.h>
#include <hip/hip_bf16.h>
#include <cstdint>
#include <cstddef>

typedef __bf16 bf16_t;
typedef __bf16 bf16x8 __attribute__((ext_vector_type(8)));
typedef float  f32x4  __attribute__((ext_vector_type(4)));

#define NB 64      // batch
#define NS 512     // source sequence length
#define NTD 128    // decoder steps
#define NE 256     // embedding dim
#define NH 512     // hidden dim
#define NG 2048    // 4*H (gates)
#define NW 256     // attention width

__device__ __forceinline__ float sigm_f(float x) { return 1.f / (1.f + __expf(-x)); }
__device__ __forceinline__ float tanh_f(float x) {
  float e = __expf(2.f * x);
  return 1.f - 2.f / (e + 1.f);
}

// Pack fp32 weight W[N][K] (used as B[k][n] = W[n][k]) into per-lane MFMA
// B-fragment order: dst[((ntile*(K/32)+kstep)*64 + lane)*8 + j]
// with n = ntile*16 + (lane&15), k = kstep*32 + (lane>>4)*8 + j.
__global__ __launch_bounds__(256) void pack_b(const float* __restrict__ src,
                                              bf16_t* __restrict__ dst,
                                              int N, int K) {
  int idx = blockIdx.x * 256 + threadIdx.x;
  if (idx >= N * K) return;
  int n = idx / K, k = idx - n * K;
  int lane = (((k & 31) >> 3) << 4) | (n & 15);
  size_t o = ((((size_t)(n >> 4) * (K >> 5)) + (k >> 5)) * 64 + lane) * 8 + (k & 7);
  dst[o] = (bf16_t)src[idx];
}

// embg[s*64+b][e] = bf16(emb_table[tokens[b][s]][e]); 8 elems per thread
__global__ __launch_bounds__(256) void gather_emb(const int* __restrict__ tokens,
                                                  const float* __restrict__ table,
                                                  bf16_t* __restrict__ embg) {
  int idx = blockIdx.x * 256 + threadIdx.x;    // over (NS*NB)*(NE/8)
  int row = idx >> 5, e0 = (idx & 31) << 3;
  int b = row & 63, s = row >> 6;
  int tok = tokens[b * NS + s];
  const float4* p = (const float4*)(table + (size_t)tok * NE + e0);
  float4 v0 = p[0], v1 = p[1];
  bf16_t* d = embg + (size_t)row * NE + e0;
  d[0] = (bf16_t)v0.x; d[1] = (bf16_t)v0.y; d[2] = (bf16_t)v0.z; d[3] = (bf16_t)v0.w;
  d[4] = (bf16_t)v1.x; d[5] = (bf16_t)v1.y; d[6] = (bf16_t)v1.z; d[7] = (bf16_t)v1.w;
}

__global__ __launch_bounds__(256) void f2b(const float* __restrict__ src,
                                           bf16_t* __restrict__ dst, int n) {
  int i = blockIdx.x * 256 + threadIdx.x;
  if (i < n) dst[i] = (bf16_t)src[i];
}
__global__ __launch_bounds__(256) void b2f(const bf16_t* __restrict__ src,
                                           float* __restrict__ dst, int n) {
  int i = blockIdx.x * 256 + threadIdx.x;
  if (i < n) dst[i] = (float)src[i];
}

// C[M][N] = A[M][K](bf16) * Bpacked + bias1(+bias2). One 16x16 tile per wave.
template <typename OutT>
__global__ __launch_bounds__(256) void gemm_bp(const bf16_t* __restrict__ A,
                                               const bf16_t* __restrict__ Bp,
                                               OutT* __restrict__ out,
                                               const float* __restrict__ bias1,
                                               const float* __restrict__ bias2,
                                               int M, int N, int K) {
  int ntiles = N >> 4, ksteps = K >> 5;
  int wid = blockIdx.x * 4 + (threadIdx.x >> 6);
  int lane = threadIdx.x & 63;
  int mt = wid / ntiles, nt = wid - mt * ntiles;
  const bf16_t* a_ptr = A + (size_t)((mt << 4) + (lane & 15)) * K + ((lane >> 4) << 3);
  const bf16_t* b_ptr = Bp + ((size_t)nt * ksteps * 64 + lane) * 8;
  f32x4 acc = {0.f, 0.f, 0.f, 0.f};
  for (int ks = 0; ks < ksteps; ++ks) {
    bf16x8 av = *(const bf16x8*)a_ptr;
    bf16x8 bv = *(const bf16x8*)b_ptr;
    acc = __builtin_amdgcn_mfma_f32_16x16x32_bf16(av, bv, acc, 0, 0, 0);
    a_ptr += 32;
    b_ptr += 512;
  }
  int col = (nt << 4) + (lane & 15);
  float bs = bias1[col] + (bias2 ? bias2[col] : 0.f);
  int rbase = (mt << 4) + ((lane >> 4) << 2);
#pragma unroll
  for (int r = 0; r < 4; ++r)
    out[(size_t)(rbase + r) * N + col] = (OutT)(acc[r] + bs);
}

// One LSTM timestep: gates = hin@Whh.T (+ xih or biases), cell update.
// grid = 32 (j-blocks of 16 h-cols), block = 1024 (16 waves: 4 gates x 4 m-tiles)
__global__ __launch_bounds__(1024) void lstm_step(const bf16_t* __restrict__ hin,
                                                  const bf16_t* __restrict__ Wp,
                                                  const bf16_t* __restrict__ xih,
                                                  const float* __restrict__ bias1,
                                                  const float* __restrict__ bias2,
                                                  float* __restrict__ cbuf,
                                                  bf16_t* __restrict__ hout) {
  __shared__ float gl[4][64][16];
  int tid = threadIdx.x, lane = tid & 63, wv = tid >> 6;
  int g = wv & 3, mt = wv >> 2, jb = blockIdx.x;
  int ntile = (g << 5) + jb;  // N=2048 -> 128 ntiles; gate g covers [g*512, g*512+512)
  const bf16_t* a_ptr = hin + (size_t)((mt << 4) + (lane & 15)) * NH + ((lane >> 4) << 3);
  const bf16_t* b_ptr = Wp + ((size_t)ntile * 16 * 64 + lane) * 8;
  f32x4 acc = {0.f, 0.f, 0.f, 0.f};
#pragma unroll
  for (int ks = 0; ks < 16; ++ks) {
    bf16x8 av = *(const bf16x8*)(a_ptr + (ks << 5));
    bf16x8 bv = *(const bf16x8*)(b_ptr + ((size_t)ks << 9));
    acc = __builtin_amdgcn_mfma_f32_16x16x32_bf16(av, bv, acc, 0, 0, 0);
  }
  int r0 = ((lane >> 4) << 2), cc = lane & 15;
#pragma unroll
  for (int r = 0; r < 4; ++r) gl[g][(mt << 4) + r0 + r][cc] = acc[r];
  __syncthreads();

  int bb = tid >> 4, jj = tid & 15, j = (jb << 4) + jj;
  float p0 = gl[0][bb][jj], p1 = gl[1][bb][jj], p2 = gl[2][bb][jj], p3 = gl[3][bb][jj];
  if (xih != nullptr) {
    const bf16_t* xr = xih + (size_t)bb * NG + j;
    p0 += (float)xr[0];
    p1 += (float)xr[NH];
    p2 += (float)xr[2 * NH];
    p3 += (float)xr[3 * NH];
  } else {
    p0 += bias1[j] + bias2[j];
    p1 += bias1[NH + j] + bias2[NH + j];
    p2 += bias1[2 * NH + j] + bias2[2 * NH + j];
    p3 += bias1[3 * NH + j] + bias2[3 * NH + j];
  }
  int ci = bb * NH + j;
  float c_old = cbuf[ci];
  float iG = sigm_f(p0), fG = sigm_f(p1), gG = tanh_f(p2), oG = sigm_f(p3);
  float cn = fG * c_old + iG * gG;
  cbuf[ci] = cn;
  hout[ci] = (bf16_t)(oG * tanh_f(cn));
}

// One WG per (t,b): u[s] = sum_w vt[w]*tanh(blend1[s,b,w]+blend2[t,b,w]),
// then log_softmax over s, write out[b][t][s]. (vt_b is a constant shift ->
// invariant under log_softmax, skipped.)
__global__ __launch_bounds__(256) void attn_kernel(const bf16_t* __restrict__ blend1,
                                                   const float* __restrict__ blend2,
                                                   const float* __restrict__ vt_w,
                                                   float* __restrict__ out) {
  __shared__ float s_vt[272], s_b2[272], s_u[512], s_red[8];
  int t = blockIdx.x >> 6;
  int b = blockIdx.x & 63;
  int tid = threadIdx.x, lane = tid & 63, wv = tid >> 6;
  {
    int ww = tid;                       // 0..255
    int pi = ww + ((ww >> 6) << 2);     // pad: +4 per 64 to kill bank conflicts
    s_vt[pi] = vt_w[ww];
    s_b2[pi] = blend2[(size_t)(t * 64 + b) * NW + ww];
  }
  __syncthreads();
  int wgrp = lane >> 4, sgrp = lane & 15;
  int base = wgrp * 68;
  for (int it = 0; it < 8; ++it) {
    int s = it * 64 + wv * 16 + sgrp;
    const bf16_t* row = blend1 + ((size_t)s * NB + b) * NW + wgrp * 64;
    float val = 0.f;
#pragma unroll
    for (int c8 = 0; c8 < 8; ++c8) {
      bf16x8 v = *(const bf16x8*)(row + c8 * 8);
#pragma unroll
      for (int jx = 0; jx < 8; ++jx) {
        int wi = base + c8 * 8 + jx;
        val += s_vt[wi] * tanh_f((float)v[jx] + s_b2[wi]);
      }
    }
    val += __shfl_xor(val, 16, 64);
    val += __shfl_xor(val, 32, 64);
    if (wgrp == 0) s_u[it * 64 + wv * 16 + sgrp] = val;
  }
  __syncthreads();
  float a = s_u[tid], bb2 = s_u[tid + 256];
  float m = fmaxf(a, bb2);
#pragma unroll
  for (int off = 1; off < 64; off <<= 1) m = fmaxf(m, __shfl_xor(m, off, 64));
  if (lane == 0) s_red[wv] = m;
  __syncthreads();
  m = fmaxf(fmaxf(s_red[0], s_red[1]), fmaxf(s_red[2], s_red[3]));
  float e = __expf(a - m) + __expf(bb2 - m);
#pragma unroll
  for (int off = 1; off < 64; off <<= 1) e += __shfl_xor(e, off, 64);
  if (lane == 0) s_red[4 + wv] = e;
  __syncthreads();
  float lz = m + logf(s_red[4] + s_red[5] + s_red[6] + s_red[7]);
  size_t ob = ((size_t)b * NTD + t) * NS;
  out[ob + tid] = a - lz;
  out[ob + tid + 256] = bb2 - lz;
}

extern "C" void kernel_launch(void* const* d_in, const int* in_sizes, int n_in,
                              void* d_out, int out_size, void* d_ws, size_t ws_size,
                              hipStream_t stream) {
  const int*   tokens    = (const int*)d_in[0];
  const float* dec_h0    = (const float*)d_in[1];
  const float* emb_table = (const float*)d_in[2];
  const float* enc_Wih   = (const float*)d_in[3];
  const float* enc_Whh   = (const float*)d_in[4];
  const float* enc_bih   = (const float*)d_in[5];
  const float* enc_bhh   = (const float*)d_in[6];
  // d_in[7] = dec_Wih: unused (decoder input is the zero vector)
  const float* dec_Whh   = (const float*)d_in[8];
  const float* dec_bih   = (const float*)d_in[9];
  const float* dec_bhh   = (const float*)d_in[10];
  const float* W1_w      = (const float*)d_in[11];
  const float* W1_b      = (const float*)d_in[12];
  const float* W2_w      = (const float*)d_in[13];
  const float* W2_b      = (const float*)d_in[14];
  const float* vt_w      = (const float*)d_in[15];
  // d_in[16] = vt_b: constant shift, invariant under log_softmax
  float* out = (float*)d_out;

  char* w = (char*)d_ws;
  size_t off = 0;
  auto alloc = [&](size_t bytes) {
    size_t o = off;
    off += (bytes + 255) & ~(size_t)255;
    return o;
  };
  bf16_t* embg   = (bf16_t*)(w + alloc((size_t)NS * NB * NE * 2));        // 16.8 MB
  bf16_t* xih    = (bf16_t*)(w + alloc((size_t)NS * NB * NG * 2));        // 134 MB
  bf16_t* enc_h  = (bf16_t*)(w + alloc((size_t)(NS + 1) * NB * NH * 2));  // 33.6 MB
  bf16_t* dec_h  = (bf16_t*)(w + alloc((size_t)(NTD + 1) * NB * NH * 2)); // 8.4 MB
  float*  cbuf   = (float*)(w + alloc((size_t)NB * NH * 4));
  bf16_t* blend1 = (bf16_t*)(w + alloc((size_t)NS * NB * NW * 2));        // 16.8 MB
  float*  blend2 = (float*)(w + alloc((size_t)NTD * NB * NW * 4));        // 8.4 MB
  bf16_t* pWih   = (bf16_t*)(w + alloc((size_t)NG * NE * 2));
  bf16_t* pWhhE  = (bf16_t*)(w + alloc((size_t)NG * NH * 2));
  bf16_t* pWhhD  = (bf16_t*)(w + alloc((size_t)NG * NH * 2));
  bf16_t* pW1    = (bf16_t*)(w + alloc((size_t)NW * NH * 2));
  bf16_t* pW2    = (bf16_t*)(w + alloc((size_t)NW * NH * 2));
  (void)ws_size; (void)in_sizes; (void)n_in; (void)out_size;

  // init: enc h0 = 0, enc c0 = 0
  hipMemsetAsync(enc_h, 0, (size_t)NB * NH * 2, stream);
  hipMemsetAsync(cbuf, 0, (size_t)NB * NH * 4, stream);

  // weight packing
  pack_b<<<(NG * NE) / 256, 256, 0, stream>>>(enc_Wih, pWih, NG, NE);
  pack_b<<<(NG * NH) / 256, 256, 0, stream>>>(enc_Whh, pWhhE, NG, NH);
  pack_b<<<(NG * NH) / 256, 256, 0, stream>>>(dec_Whh, pWhhD, NG, NH);
  pack_b<<<(NW * NH) / 256, 256, 0, stream>>>(W1_w, pW1, NW, NH);
  pack_b<<<(NW * NH) / 256, 256, 0, stream>>>(W2_w, pW2, NW, NH);

  // embedding gather (bf16), decoder h0 -> bf16
  gather_emb<<<(NS * NB * (NE / 8)) / 256, 256, 0, stream>>>(tokens, emb_table, embg);
  f2b<<<(NB * NH) / 256, 256, 0, stream>>>(dec_h0, dec_h, NB * NH);

  // Xih[s*64+b][4H] = embg @ Wih.T + bih + bhh   (hoisted out of the chain)
  gemm_bp<bf16_t><<<(2048 * 128) / 4, 256, 0, stream>>>(
      embg, pWih, xih, enc_bih, enc_bhh, NS * NB, NG, NE);

  // encoder chain
  for (int s = 0; s < NS; ++s) {
    lstm_step<<<32, 1024, 0, stream>>>(enc_h + (size_t)s * NB * NH, pWhhE,
                                       xih + (size_t)s * NB * NG, nullptr, nullptr,
                                       cbuf, enc_h + (size_t)(s + 1) * NB * NH);
  }
  // decoder c0 = last encoder h
  b2f<<<(NB * NH) / 256, 256, 0, stream>>>(enc_h + (size_t)NS * NB * NH, cbuf, NB * NH);

  // blend1 = enc_states @ W1.T + W1_b  (bf16, [s*64+b][W])
  gemm_bp<bf16_t><<<(2048 * 16) / 4, 256, 0, stream>>>(
      enc_h + (size_t)NB * NH, pW1, blend1, W1_b, nullptr, NS * NB, NW, NH);

  // decoder chain (x = 0 -> only h@Whh + biases)
  for (int t = 0; t < NTD; ++t) {
    lstm_step<<<32, 1024, 0, stream>>>(dec_h + (size_t)t * NB * NH, pWhhD,
                                       nullptr, dec_bih, dec_bhh, cbuf,
                                       dec_h + (size_t)(t + 1) * NB * NH);
  }

  // blend2 = dec_h @ W2.T + W2_b  (fp32, [t*64+b][W])
  gemm_bp<float><<<(512 * 16) / 4, 256, 0, stream>>>(
      dec_h + (size_t)NB * NH, pW2, blend2, W2_b, nullptr, NTD * NB, NW, NH);

  // attention + log_softmax + output [B,T,S]
  attn_kernel<<<NTD * NB, 256, 0, stream>>>(blend1, blend2, vt_w, out);
}

// Round 3
// 4127.610 us; speedup vs baseline: 2.0430x; 2.0430x over previous
//
#include <hip/hip_runtime.h>
#include <hip/hip_bf16.h>
#include <cstdint>
#include <cstddef>

typedef __bf16 bf16_t;
typedef __bf16 bf16x8 __attribute__((ext_vector_type(8)));
typedef float  f32x4  __attribute__((ext_vector_type(4)));

#define NB 64      // batch
#define NS 512     // source sequence length
#define NTD 128    // decoder steps
#define NE 256     // embedding dim
#define NH 512     // hidden dim
#define NG 2048    // 4*H (gates)
#define NW 256     // attention width

// one timestep of h in fragment layout = [4 bg][16 ks][64 lanes][4 dwords]
#define HSTEP_DW 16384u

__device__ __forceinline__ float sigm_f(float x) { return 1.f / (1.f + __expf(-x)); }
__device__ __forceinline__ float tanh_f(float x) {
  float e = __expf(2.f * x);
  return 1.f - 2.f / (e + 1.f);
}
__device__ __forceinline__ float bits2f(uint32_t b16) {
  uint32_t u = b16 << 16;
  return __builtin_bit_cast(float, u);
}
__device__ __forceinline__ uint32_t packh(float a, float b) {
  uint16_t lo = __builtin_bit_cast(uint16_t, (bf16_t)a);
  uint16_t hi = __builtin_bit_cast(uint16_t, (bf16_t)b);
  return (uint32_t)lo | ((uint32_t)hi << 16);
}

// Pack fp32 weight W[N][K] (used as B[k][n] = W[n][k]) into per-lane MFMA
// B-fragment order: dst[((ntile*(K/32)+kstep)*64 + lane)*8 + j]
// with n = ntile*16 + (lane&15), k = kstep*32 + (lane>>4)*8 + j.
__global__ __launch_bounds__(256) void pack_b(const float* __restrict__ src,
                                              bf16_t* __restrict__ dst,
                                              int N, int K) {
  int idx = blockIdx.x * 256 + threadIdx.x;
  if (idx >= N * K) return;
  int n = idx / K, k = idx - n * K;
  int lane = (((k & 31) >> 3) << 4) | (n & 15);
  size_t o = ((((size_t)(n >> 4) * (K >> 5)) + (k >> 5)) * 64 + lane) * 8 + (k & 7);
  dst[o] = (bf16_t)src[idx];
}

// Embedding gather writing A-FRAGMENT layout:
// embfrag[((mt*8 + kstep)*64 + lane)*8 + elem], mt = (s*64+b)>>4.
__global__ __launch_bounds__(256) void gather_emb(const int* __restrict__ tokens,
                                                  const float* __restrict__ table,
                                                  bf16_t* __restrict__ embfrag) {
  int idx = blockIdx.x * 256 + threadIdx.x;    // over (NS*NB)*(NE/8)
  int row = idx >> 5, e0 = (idx & 31) << 3;
  int b = row & 63, s = row >> 6;
  int tok = tokens[b * NS + s];
  const float4* p = (const float4*)(table + (size_t)tok * NE + e0);
  float4 v0 = p[0], v1 = p[1];
  bf16x8 v;
  v[0] = (bf16_t)v0.x; v[1] = (bf16_t)v0.y; v[2] = (bf16_t)v0.z; v[3] = (bf16_t)v0.w;
  v[4] = (bf16_t)v1.x; v[5] = (bf16_t)v1.y; v[6] = (bf16_t)v1.z; v[7] = (bf16_t)v1.w;
  int mt = row >> 4;
  int ks = e0 >> 5;
  int lane = (b & 15) | (((e0 >> 3) & 3) << 4);
  *(bf16x8*)(embfrag + ((size_t)(mt * 8 + ks) * 64 + lane) * 8) = v;
}

// dec_h0 fp32 [64][512] -> fragment layout dword buffer (step 0 of dec hfrag)
__global__ __launch_bounds__(256) void pack_h0(const float* __restrict__ src,
                                               uint32_t* __restrict__ dst) {
  int idx = blockIdx.x * 256 + threadIdx.x;  // 0..16383 (dword id)
  int b = idx >> 8, jp = idx & 255;
  int j = jp * 2;
  float lo = src[(size_t)b * NH + j], hi = src[(size_t)b * NH + j + 1];
  int bg = b >> 4, bl = b & 15, ks = j >> 5;
  int lane = bl | (((j >> 3) & 3) << 4);
  dst[((size_t)bg * 16 + ks) * 256 + lane * 4 + ((j >> 1) & 3)] = packh(lo, hi);
}

// C[M][N] = Afrag * Bpacked + bias1(+bias2). A in fragment layout
// (per m-tile: ksteps blocks of [64 lanes][8 bf16]). One 16x16 tile per wave.
template <typename OutT>
__global__ __launch_bounds__(256) void gemm_fa(const bf16_t* __restrict__ A,
                                               const bf16_t* __restrict__ Bp,
                                               OutT* __restrict__ out,
                                               const float* __restrict__ bias1,
                                               const float* __restrict__ bias2,
                                               int N, int K) {
  int ntiles = N >> 4, ksteps = K >> 5;
  int wid = blockIdx.x * 4 + (threadIdx.x >> 6);
  int lane = threadIdx.x & 63;
  int mt = wid / ntiles, nt = wid - mt * ntiles;
  const bf16_t* a_ptr = A + ((size_t)mt * ksteps) * 512 + lane * 8;
  const bf16_t* b_ptr = Bp + ((size_t)nt * ksteps * 64 + lane) * 8;
  f32x4 acc = {0.f, 0.f, 0.f, 0.f};
  for (int ks = 0; ks < ksteps; ++ks) {
    bf16x8 av = *(const bf16x8*)(a_ptr + (size_t)ks * 512);
    bf16x8 bv = *(const bf16x8*)(b_ptr + (size_t)ks * 512);
    acc = __builtin_amdgcn_mfma_f32_16x16x32_bf16(av, bv, acc, 0, 0, 0);
  }
  int col = (nt << 4) + (lane & 15);
  float bs = bias1[col] + (bias2 ? bias2[col] : 0.f);
  int rbase = (mt << 4) + ((lane >> 4) << 2);
#pragma unroll
  for (int r = 0; r < 4; ++r)
    out[(size_t)(rbase + r) * N + col] = (OutT)(acc[r] + bs);
}

// Persistent LSTM chain. Grid = 64 WGs x 256 thr: bg = blockIdx>>4 (batch
// group of 16), slice = blockIdx&15 (owns h cols [slice*32, slice*32+32)).
// Whh slice (128 gate-cols x 512) lives in LDS for all T steps. h exchanged
// through global memory in MFMA fragment layout via agent-scope atomics;
// per-group barrier = release atomicAdd + acquire spin on cnt[bg].
template <bool USE_XIH>
__global__ __launch_bounds__(256) void lstm_chain(
    const bf16_t* __restrict__ Wp,   // packed [128 ntiles][16 ks][64][8]
    const bf16_t* __restrict__ xih,  // [T*64][2048] bf16, or nullptr
    const float* __restrict__ bih, const float* __restrict__ bhh,
    uint32_t* __restrict__ hfrag,    // dword view: [T+1][4 bg][16 ks][64][4]
    const uint32_t* __restrict__ c0frag,  // init c (bf16-pair dwords) or null
    uint32_t* __restrict__ cnt, int T) {
  __shared__ bf16_t wlds[8 * 8192];      // 128 KB
  __shared__ float gl[4][16][36];        // gate exchange, padded
  int tid = threadIdx.x, lane = tid & 63, wv = tid >> 6;
  int bg = blockIdx.x >> 4, slice = blockIdx.x & 15;

  // stage packed weight slice: 8 ntiles (4 gates x 2) of 16 KB each
  for (int l = 0; l < 8; ++l) {
    int g = l >> 1, p = l & 1;
    const bf16_t* src = Wp + (size_t)(g * 32 + slice * 2 + p) * 8192;
    bf16_t* dst = wlds + (size_t)l * 8192;
    for (int i = tid; i < 1024; i += 256)
      *(bf16x8*)(dst + (size_t)i * 8) = *(const bf16x8*)(src + (size_t)i * 8);
  }

  int ub = tid >> 4, uj2 = tid & 15;     // this thread owns (batch ub, j pair uj2)
  int j_lo = slice * 32 + uj2 * 2;
  int lane_f = ub | ((uj2 >> 2) << 4);   // fragment lane for j pair
  float c0 = 0.f, c1 = 0.f;
  if (c0frag != nullptr) {
    uint32_t d = c0frag[((size_t)bg * 16 + slice) * 256 + lane_f * 4 + (uj2 & 3)];
    c0 = bits2f(d & 0xffffu);
    c1 = bits2f(d >> 16);
  }
  float bsum[4][2];
  if (!USE_XIH) {
#pragma unroll
    for (int g = 0; g < 4; ++g) {
      bsum[g][0] = bih[g * NH + j_lo] + bhh[g * NH + j_lo];
      bsum[g][1] = bih[g * NH + j_lo + 1] + bhh[g * NH + j_lo + 1];
    }
  }
  __syncthreads();

  const uint64_t* hq = (const uint64_t*)hfrag;
  uint32_t* myc = cnt + bg;

  for (int t = 0; t < T; ++t) {
    // A fragments of h_t: 16 ksteps x 16B per lane, coalesced agent loads
    const uint64_t* hb = hq + ((size_t)t * 4 + bg) * 2048 + lane * 2;
    uint64_t aq[16][2];
#pragma unroll
    for (int ks = 0; ks < 16; ++ks) {
      aq[ks][0] = __hip_atomic_load(hb + (size_t)ks * 128,
                                    __ATOMIC_RELAXED, __HIP_MEMORY_SCOPE_AGENT);
      aq[ks][1] = __hip_atomic_load(hb + (size_t)ks * 128 + 1,
                                    __ATOMIC_RELAXED, __HIP_MEMORY_SCOPE_AGENT);
    }
    // wave wv computes gate wv over this slice's 32 cols (2 n-tiles)
    const bf16_t* wl = wlds + (size_t)(wv * 2) * 8192 + lane * 8;
    f32x4 acc0 = {0.f, 0.f, 0.f, 0.f}, acc1 = {0.f, 0.f, 0.f, 0.f};
#pragma unroll
    for (int ks = 0; ks < 16; ++ks) {
      union { uint64_t q[2]; bf16x8 v; } u;
      u.q[0] = aq[ks][0]; u.q[1] = aq[ks][1];
      acc0 = __builtin_amdgcn_mfma_f32_16x16x32_bf16(
          u.v, *(const bf16x8*)(wl + (size_t)ks * 512), acc0, 0, 0, 0);
      acc1 = __builtin_amdgcn_mfma_f32_16x16x32_bf16(
          u.v, *(const bf16x8*)(wl + 8192 + (size_t)ks * 512), acc1, 0, 0, 0);
    }
    int cc = lane & 15, rb = (lane >> 4) << 2;
#pragma unroll
    for (int r = 0; r < 4; ++r) {
      gl[wv][rb + r][cc] = acc0[r];
      gl[wv][rb + r][16 + cc] = acc1[r];
    }
    __syncthreads();

    // cell update for (ub, j_lo), (ub, j_lo+1)
    float p[4][2];
#pragma unroll
    for (int g = 0; g < 4; ++g) {
      p[g][0] = gl[g][ub][uj2 * 2];
      p[g][1] = gl[g][ub][uj2 * 2 + 1];
    }
    if (USE_XIH) {
      const uint32_t* xr = (const uint32_t*)xih +
          ((size_t)(t * 64 + bg * 16 + ub)) * 1024 + slice * 16 + uj2;
#pragma unroll
      for (int g = 0; g < 4; ++g) {
        uint32_t d = xr[(size_t)g * 256];
        p[g][0] += bits2f(d & 0xffffu);
        p[g][1] += bits2f(d >> 16);
      }
    } else {
#pragma unroll
      for (int g = 0; g < 4; ++g) { p[g][0] += bsum[g][0]; p[g][1] += bsum[g][1]; }
    }
    float i0 = sigm_f(p[0][0]), f0 = sigm_f(p[1][0]);
    float g0 = tanh_f(p[2][0]), o0 = sigm_f(p[3][0]);
    c0 = f0 * c0 + i0 * g0;
    float h0 = o0 * tanh_f(c0);
    float i1 = sigm_f(p[0][1]), f1 = sigm_f(p[1][1]);
    float g1 = tanh_f(p[2][1]), o1 = sigm_f(p[3][1]);
    c1 = f1 * c1 + i1 * g1;
    float h1 = o1 * tanh_f(c1);
    // store h_{t+1} pair directly in fragment layout (kstep == slice)
    __hip_atomic_store(hfrag + ((size_t)(t + 1) * 4 + bg) * 4096 +
                           slice * 256 + lane_f * 4 + (uj2 & 3),
                       packh(h0, h1), __ATOMIC_RELAXED, __HIP_MEMORY_SCOPE_AGENT);
    __syncthreads();   // all stores issued & drained (waitcnt before barrier)
    if (tid == 0) {
      __hip_atomic_fetch_add(myc, 1u, __ATOMIC_RELEASE, __HIP_MEMORY_SCOPE_AGENT);
      uint32_t tgt = 16u * (uint32_t)(t + 1);
      while (__hip_atomic_load(myc, __ATOMIC_ACQUIRE, __HIP_MEMORY_SCOPE_AGENT) < tgt) {}
    }
    __syncthreads();
  }
}

// One WG per (t,b): u[s] = sum_w vt[w]*tanh(blend1[s,b,w]+blend2[t,b,w]),
// then log_softmax over s, write out[b][t][s].
__global__ __launch_bounds__(256) void attn_kernel(const bf16_t* __restrict__ blend1,
                                                   const float* __restrict__ blend2,
                                                   const float* __restrict__ vt_w,
                                                   float* __restrict__ out) {
  __shared__ float s_vt[272], s_b2[272], s_u[512], s_red[8];
  int t = blockIdx.x >> 6;
  int b = blockIdx.x & 63;
  int tid = threadIdx.x, lane = tid & 63, wv = tid >> 6;
  {
    int ww = tid;
    int pi = ww + ((ww >> 6) << 2);
    s_vt[pi] = vt_w[ww];
    s_b2[pi] = blend2[(size_t)(t * 64 + b) * NW + ww];
  }
  __syncthreads();
  int wgrp = lane >> 4, sgrp = lane & 15;
  int base = wgrp * 68;
  for (int it = 0; it < 8; ++it) {
    int s = it * 64 + wv * 16 + sgrp;
    const bf16_t* row = blend1 + ((size_t)s * NB + b) * NW + wgrp * 64;
    float val = 0.f;
#pragma unroll
    for (int c8 = 0; c8 < 8; ++c8) {
      bf16x8 v = *(const bf16x8*)(row + c8 * 8);
#pragma unroll
      for (int jx = 0; jx < 8; ++jx) {
        int wi = base + c8 * 8 + jx;
        val += s_vt[wi] * tanh_f((float)v[jx] + s_b2[wi]);
      }
    }
    val += __shfl_xor(val, 16, 64);
    val += __shfl_xor(val, 32, 64);
    if (wgrp == 0) s_u[it * 64 + wv * 16 + sgrp] = val;
  }
  __syncthreads();
  float a = s_u[tid], bb2 = s_u[tid + 256];
  float m = fmaxf(a, bb2);
#pragma unroll
  for (int off = 1; off < 64; off <<= 1) m = fmaxf(m, __shfl_xor(m, off, 64));
  if (lane == 0) s_red[wv] = m;
  __syncthreads();
  m = fmaxf(fmaxf(s_red[0], s_red[1]), fmaxf(s_red[2], s_red[3]));
  float e = __expf(a - m) + __expf(bb2 - m);
#pragma unroll
  for (int off = 1; off < 64; off <<= 1) e += __shfl_xor(e, off, 64);
  if (lane == 0) s_red[4 + wv] = e;
  __syncthreads();
  float lz = m + logf(s_red[4] + s_red[5] + s_red[6] + s_red[7]);
  size_t ob = ((size_t)b * NTD + t) * NS;
  out[ob + tid] = a - lz;
  out[ob + tid + 256] = bb2 - lz;
}

extern "C" void kernel_launch(void* const* d_in, const int* in_sizes, int n_in,
                              void* d_out, int out_size, void* d_ws, size_t ws_size,
                              hipStream_t stream) {
  const int*   tokens    = (const int*)d_in[0];
  const float* dec_h0    = (const float*)d_in[1];
  const float* emb_table = (const float*)d_in[2];
  const float* enc_Wih   = (const float*)d_in[3];
  const float* enc_Whh   = (const float*)d_in[4];
  const float* enc_bih   = (const float*)d_in[5];
  const float* enc_bhh   = (const float*)d_in[6];
  // d_in[7] = dec_Wih: unused (decoder input is the zero vector)
  const float* dec_Whh   = (const float*)d_in[8];
  const float* dec_bih   = (const float*)d_in[9];
  const float* dec_bhh   = (const float*)d_in[10];
  const float* W1_w      = (const float*)d_in[11];
  const float* W1_b      = (const float*)d_in[12];
  const float* W2_w      = (const float*)d_in[13];
  const float* W2_b      = (const float*)d_in[14];
  const float* vt_w      = (const float*)d_in[15];
  // d_in[16] = vt_b: constant shift, invariant under log_softmax
  float* out = (float*)d_out;

  char* w = (char*)d_ws;
  size_t off = 0;
  auto alloc = [&](size_t bytes) {
    size_t o = off;
    off += (bytes + 255) & ~(size_t)255;
    return o;
  };
  bf16_t* embfrag = (bf16_t*)(w + alloc((size_t)NS * NB * NE * 2));          // 16.8 MB
  bf16_t* xih     = (bf16_t*)(w + alloc((size_t)NS * NB * NG * 2));          // 134 MB
  uint32_t* enc_hf = (uint32_t*)(w + alloc((size_t)(NS + 1) * HSTEP_DW * 4)); // 33.6 MB
  uint32_t* dec_hf = (uint32_t*)(w + alloc((size_t)(NTD + 1) * HSTEP_DW * 4)); // 8.5 MB
  bf16_t* blend1  = (bf16_t*)(w + alloc((size_t)NS * NB * NW * 2));          // 16.8 MB
  float*  blend2  = (float*)(w + alloc((size_t)NTD * NB * NW * 4));          // 8.4 MB
  bf16_t* pWih    = (bf16_t*)(w + alloc((size_t)NG * NE * 2));
  bf16_t* pWhhE   = (bf16_t*)(w + alloc((size_t)NG * NH * 2));
  bf16_t* pWhhD   = (bf16_t*)(w + alloc((size_t)NG * NH * 2));
  bf16_t* pW1     = (bf16_t*)(w + alloc((size_t)NW * NH * 2));
  bf16_t* pW2     = (bf16_t*)(w + alloc((size_t)NW * NH * 2));
  uint32_t* cnt   = (uint32_t*)(w + alloc(256));
  (void)ws_size; (void)in_sizes; (void)n_in; (void)out_size;

  // per-call init: barrier counters, encoder h0 = 0 (step-0 fragment block)
  hipMemsetAsync(cnt, 0, 64, stream);
  hipMemsetAsync(enc_hf, 0, HSTEP_DW * 4, stream);

  // weight packing
  pack_b<<<(NG * NE) / 256, 256, 0, stream>>>(enc_Wih, pWih, NG, NE);
  pack_b<<<(NG * NH) / 256, 256, 0, stream>>>(enc_Whh, pWhhE, NG, NH);
  pack_b<<<(NG * NH) / 256, 256, 0, stream>>>(dec_Whh, pWhhD, NG, NH);
  pack_b<<<(NW * NH) / 256, 256, 0, stream>>>(W1_w, pW1, NW, NH);
  pack_b<<<(NW * NH) / 256, 256, 0, stream>>>(W2_w, pW2, NW, NH);

  // embedding gather (fragment layout), decoder h0 pack
  gather_emb<<<(NS * NB * (NE / 8)) / 256, 256, 0, stream>>>(tokens, emb_table, embfrag);
  pack_h0<<<64, 256, 0, stream>>>(dec_h0, dec_hf);

  // Xih = emb @ Wih.T + bih + bhh  (hoisted; normal row layout bf16)
  gemm_fa<bf16_t><<<(2048 * 128) / 4, 256, 0, stream>>>(
      embfrag, pWih, xih, enc_bih, enc_bhh, NG, NE);

  // encoder chain (persistent, 512 steps)
  lstm_chain<true><<<64, 256, 0, stream>>>(pWhhE, xih, nullptr, nullptr,
                                           enc_hf, nullptr, cnt, NS);

  // blend1 = enc_states @ W1.T + W1_b (A = enc fragments, skip step 0)
  gemm_fa<bf16_t><<<(2048 * 16) / 4, 256, 0, stream>>>(
      (const bf16_t*)(enc_hf + HSTEP_DW), pW1, blend1, W1_b, nullptr, NW, NH);

  // decoder chain (128 steps); c0 = last encoder h (fragment block 512)
  lstm_chain<false><<<64, 256, 0, stream>>>(pWhhD, nullptr, dec_bih, dec_bhh,
                                            dec_hf, enc_hf + (size_t)NS * HSTEP_DW,
                                            cnt + 4, NTD);

  // blend2 = dec_h @ W2.T + W2_b (fp32, A = dec fragments, skip step 0)
  gemm_fa<float><<<(512 * 16) / 4, 256, 0, stream>>>(
      (const bf16_t*)(dec_hf + HSTEP_DW), pW2, blend2, W2_b, nullptr, NW, NH);

  // attention + log_softmax -> out [B,T,S]
  attn_kernel<<<NTD * NB, 256, 0, stream>>>(blend1, blend2, vt_w, out);
}

// Round 4
// 2865.566 us; speedup vs baseline: 2.9428x; 1.4404x over previous
//
#include <hip/hip_runtime.h>
#include <hip/hip_bf16.h>
#include <cstdint>
#include <cstddef>

typedef __bf16 bf16_t;
typedef __bf16 bf16x8 __attribute__((ext_vector_type(8)));
typedef float  f32x4  __attribute__((ext_vector_type(4)));

#define NB 64      // batch
#define NS 512     // source sequence length
#define NTD 128    // decoder steps
#define NE 256     // embedding dim
#define NH 512     // hidden dim
#define NG 2048    // 4*H (gates)
#define NW 256     // attention width

// one timestep of h in fragment layout = [4 bg][16 ks][64 lanes][4 dwords]
#define HSTEP_DW 16384u

__device__ __forceinline__ float sigm_f(float x) { return 1.f / (1.f + __expf(-x)); }
__device__ __forceinline__ float tanh_f(float x) {
  float e = __expf(2.f * x);
  return 1.f - 2.f / (e + 1.f);
}
__device__ __forceinline__ float bits2f(uint32_t b16) {
  uint32_t u = b16 << 16;
  return __builtin_bit_cast(float, u);
}
__device__ __forceinline__ uint32_t packh(float a, float b) {
  uint16_t lo = __builtin_bit_cast(uint16_t, (bf16_t)a);
  uint16_t hi = __builtin_bit_cast(uint16_t, (bf16_t)b);
  return (uint32_t)lo | ((uint32_t)hi << 16);
}

// Pack fp32 weight W[N][K] (used as B[k][n] = W[n][k]) into per-lane MFMA
// B-fragment order: dst[((ntile*(K/32)+kstep)*64 + lane)*8 + j]
// with n = ntile*16 + (lane&15), k = kstep*32 + (lane>>4)*8 + j.
__global__ __launch_bounds__(256) void pack_b(const float* __restrict__ src,
                                              bf16_t* __restrict__ dst,
                                              int N, int K) {
  int idx = blockIdx.x * 256 + threadIdx.x;
  if (idx >= N * K) return;
  int n = idx / K, k = idx - n * K;
  int lane = (((k & 31) >> 3) << 4) | (n & 15);
  size_t o = ((((size_t)(n >> 4) * (K >> 5)) + (k >> 5)) * 64 + lane) * 8 + (k & 7);
  dst[o] = (bf16_t)src[idx];
}

// Embedding gather writing A-FRAGMENT layout:
// embfrag[((mt*8 + kstep)*64 + lane)*8 + elem], mt = (s*64+b)>>4.
__global__ __launch_bounds__(256) void gather_emb(const int* __restrict__ tokens,
                                                  const float* __restrict__ table,
                                                  bf16_t* __restrict__ embfrag) {
  int idx = blockIdx.x * 256 + threadIdx.x;    // over (NS*NB)*(NE/8)
  int row = idx >> 5, e0 = (idx & 31) << 3;
  int b = row & 63, s = row >> 6;
  int tok = tokens[b * NS + s];
  const float4* p = (const float4*)(table + (size_t)tok * NE + e0);
  float4 v0 = p[0], v1 = p[1];
  bf16x8 v;
  v[0] = (bf16_t)v0.x; v[1] = (bf16_t)v0.y; v[2] = (bf16_t)v0.z; v[3] = (bf16_t)v0.w;
  v[4] = (bf16_t)v1.x; v[5] = (bf16_t)v1.y; v[6] = (bf16_t)v1.z; v[7] = (bf16_t)v1.w;
  int mt = row >> 4;
  int ks = e0 >> 5;
  int lane = (b & 15) | (((e0 >> 3) & 3) << 4);
  *(bf16x8*)(embfrag + ((size_t)(mt * 8 + ks) * 64 + lane) * 8) = v;
}

// dec_h0 fp32 [64][512] -> fragment layout dword buffer (step 0 of dec hfrag)
__global__ __launch_bounds__(256) void pack_h0(const float* __restrict__ src,
                                               uint32_t* __restrict__ dst) {
  int idx = blockIdx.x * 256 + threadIdx.x;  // 0..16383 (dword id)
  int b = idx >> 8, jp = idx & 255;
  int j = jp * 2;
  float lo = src[(size_t)b * NH + j], hi = src[(size_t)b * NH + j + 1];
  int bg = b >> 4, bl = b & 15, ks = j >> 5;
  int lane = bl | (((j >> 3) & 3) << 4);
  dst[((size_t)bg * 16 + ks) * 256 + lane * 4 + ((j >> 1) & 3)] = packh(lo, hi);
}

// Tiled GEMM: C[M][N] = Afrag * Bpacked + bias1(+bias2).
// grid = (N/64, mtiles/MT), block = 256 (4 waves). Wave w owns n-tile
// blockIdx.x*4+w, holds its B fragments (KS x bf16x8) in registers, loops
// over MT m-tiles (A chunk shared by the 4 waves -> L1/L2 hits).
template <typename OutT, int KS, int MT>
__global__ __launch_bounds__(256) void gemm_fa2(const bf16_t* __restrict__ A,
                                                const bf16_t* __restrict__ Bp,
                                                OutT* __restrict__ out,
                                                const float* __restrict__ bias1,
                                                const float* __restrict__ bias2,
                                                int N) {
  int lane = threadIdx.x & 63, w = threadIdx.x >> 6;
  int nt = blockIdx.x * 4 + w;
  int mt0 = blockIdx.y * MT;
  bf16x8 bfr[KS];
  const bf16_t* bp = Bp + ((size_t)nt * KS * 64 + lane) * 8;
#pragma unroll
  for (int ks = 0; ks < KS; ++ks) bfr[ks] = *(const bf16x8*)(bp + (size_t)ks * 512);
  int col = (nt << 4) + (lane & 15);
  float bs = bias1[col] + (bias2 ? bias2[col] : 0.f);
  for (int m = 0; m < MT; ++m) {
    int mt = mt0 + m;
    const bf16_t* ap = A + (size_t)mt * (KS * 512) + lane * 8;
    f32x4 acc = {0.f, 0.f, 0.f, 0.f};
#pragma unroll
    for (int ks = 0; ks < KS; ++ks)
      acc = __builtin_amdgcn_mfma_f32_16x16x32_bf16(
          *(const bf16x8*)(ap + (size_t)ks * 512), bfr[ks], acc, 0, 0, 0);
    int rbase = (mt << 4) + ((lane >> 4) << 2);
#pragma unroll
    for (int r = 0; r < 4; ++r)
      out[(size_t)(rbase + r) * N + col] = (OutT)(acc[r] + bs);
  }
}

// Persistent LSTM chain. Grid = 64 WGs x 256 thr: bg = blockIdx>>4 (batch
// group of 16), slice = blockIdx&15 (owns h cols [slice*32, slice*32+32)).
// Whh slice (128 gate-cols x 512) lives in LDS for all T steps. h exchanged
// through global memory in MFMA fragment layout via RELAXED agent-scope
// atomics (L2-bypassing, L3-coherent). Per-step sync: after __syncthreads
// drains all h stores to L3, tid0 stores flag[slice]=t+1 (relaxed); consumer
// waves poll the 16 flags (lanes 0-15, own slice skipped). No acquire/
// release -> no L2 writeback/invalidate storms.
template <bool USE_XIH>
__global__ __launch_bounds__(256) void lstm_chain(
    const bf16_t* __restrict__ Wp,   // packed [128 ntiles][16 ks][64][8]
    const bf16_t* __restrict__ xih,  // [T*64][2048] bf16, or nullptr
    const float* __restrict__ bih, const float* __restrict__ bhh,
    uint32_t* __restrict__ hfrag,    // dword view: [T+1][4 bg][16 ks][64][4]
    const uint32_t* __restrict__ c0frag,  // init c (bf16-pair dwords) or null
    uint32_t* __restrict__ flags,    // [4 bg][16 slices], pre-zeroed
    int T) {
  __shared__ bf16_t wlds[8 * 8192];      // 128 KB
  __shared__ float gl[4][16][36];        // gate exchange, padded
  int tid = threadIdx.x, lane = tid & 63, wv = tid >> 6;
  int bg = blockIdx.x >> 4, slice = blockIdx.x & 15;

  // stage packed weight slice: 8 ntiles (4 gates x 2) of 16 KB each
  for (int l = 0; l < 8; ++l) {
    int g = l >> 1, p = l & 1;
    const bf16_t* src = Wp + (size_t)(g * 32 + slice * 2 + p) * 8192;
    bf16_t* dst = wlds + (size_t)l * 8192;
    for (int i = tid; i < 1024; i += 256)
      *(bf16x8*)(dst + (size_t)i * 8) = *(const bf16x8*)(src + (size_t)i * 8);
  }

  int ub = tid >> 4, uj2 = tid & 15;     // this thread owns (batch ub, j pair uj2)
  int j_lo = slice * 32 + uj2 * 2;
  int lane_f = ub | ((uj2 >> 2) << 4);   // fragment lane for j pair
  float c0 = 0.f, c1 = 0.f;
  if (c0frag != nullptr) {
    uint32_t d = c0frag[((size_t)bg * 16 + slice) * 256 + lane_f * 4 + (uj2 & 3)];
    c0 = bits2f(d & 0xffffu);
    c1 = bits2f(d >> 16);
  }
  float bsum[4][2];
  if (!USE_XIH) {
#pragma unroll
    for (int g = 0; g < 4; ++g) {
      bsum[g][0] = bih[g * NH + j_lo] + bhh[g * NH + j_lo];
      bsum[g][1] = bih[g * NH + j_lo + 1] + bhh[g * NH + j_lo + 1];
    }
  }
  __syncthreads();

  const uint64_t* hq = (const uint64_t*)hfrag;
  uint32_t* fl = flags + bg * 16;

  for (int t = 0; t < T; ++t) {
    // xih prefetch for this step (plain loads; latency hides under the spin)
    uint32_t xd[4];
    if (USE_XIH) {
      const uint32_t* xr = (const uint32_t*)xih +
          ((size_t)(t * 64 + bg * 16 + ub)) * 1024 + slice * 16 + uj2;
#pragma unroll
      for (int g = 0; g < 4; ++g) xd[g] = xr[(size_t)g * 256];
    }
    // wait for h_t: every wave polls the 16 flags (own slice's data was
    // already drained to L3 by our own previous __syncthreads -> skip it)
    if (t > 0) {
      uint32_t tgt = (uint32_t)t;
      bool ok;
      do {
        uint32_t f = tgt;
        if (lane < 16 && lane != (uint32_t)slice)
          f = __hip_atomic_load(fl + lane, __ATOMIC_RELAXED,
                                __HIP_MEMORY_SCOPE_AGENT);
        ok = __all(f >= tgt);
      } while (!ok);
    }
    // A fragments of h_t: 16 ksteps x 16B per lane, coalesced agent loads
    const uint64_t* hb = hq + ((size_t)t * 4 + bg) * 2048 + lane * 2;
    uint64_t aq[16][2];
#pragma unroll
    for (int ks = 0; ks < 16; ++ks) {
      aq[ks][0] = __hip_atomic_load(hb + (size_t)ks * 128,
                                    __ATOMIC_RELAXED, __HIP_MEMORY_SCOPE_AGENT);
      aq[ks][1] = __hip_atomic_load(hb + (size_t)ks * 128 + 1,
                                    __ATOMIC_RELAXED, __HIP_MEMORY_SCOPE_AGENT);
    }
    // wave wv computes gate wv over this slice's 32 cols (2 n-tiles)
    const bf16_t* wl = wlds + (size_t)(wv * 2) * 8192 + lane * 8;
    f32x4 acc0 = {0.f, 0.f, 0.f, 0.f}, acc1 = {0.f, 0.f, 0.f, 0.f};
#pragma unroll
    for (int ks = 0; ks < 16; ++ks) {
      union { uint64_t q[2]; bf16x8 v; } u;
      u.q[0] = aq[ks][0]; u.q[1] = aq[ks][1];
      acc0 = __builtin_amdgcn_mfma_f32_16x16x32_bf16(
          u.v, *(const bf16x8*)(wl + (size_t)ks * 512), acc0, 0, 0, 0);
      acc1 = __builtin_amdgcn_mfma_f32_16x16x32_bf16(
          u.v, *(const bf16x8*)(wl + 8192 + (size_t)ks * 512), acc1, 0, 0, 0);
    }
    int cc = lane & 15, rb = (lane >> 4) << 2;
#pragma unroll
    for (int r = 0; r < 4; ++r) {
      gl[wv][rb + r][cc] = acc0[r];
      gl[wv][rb + r][16 + cc] = acc1[r];
    }
    __syncthreads();

    // cell update for (ub, j_lo), (ub, j_lo+1)
    float p[4][2];
#pragma unroll
    for (int g = 0; g < 4; ++g) {
      p[g][0] = gl[g][ub][uj2 * 2];
      p[g][1] = gl[g][ub][uj2 * 2 + 1];
    }
    if (USE_XIH) {
#pragma unroll
      for (int g = 0; g < 4; ++g) {
        p[g][0] += bits2f(xd[g] & 0xffffu);
        p[g][1] += bits2f(xd[g] >> 16);
      }
    } else {
#pragma unroll
      for (int g = 0; g < 4; ++g) { p[g][0] += bsum[g][0]; p[g][1] += bsum[g][1]; }
    }
    float i0 = sigm_f(p[0][0]), f0 = sigm_f(p[1][0]);
    float g0 = tanh_f(p[2][0]), o0 = sigm_f(p[3][0]);
    c0 = f0 * c0 + i0 * g0;
    float h0 = o0 * tanh_f(c0);
    float i1 = sigm_f(p[0][1]), f1 = sigm_f(p[1][1]);
    float g1 = tanh_f(p[2][1]), o1 = sigm_f(p[3][1]);
    c1 = f1 * c1 + i1 * g1;
    float h1 = o1 * tanh_f(c1);
    // store h_{t+1} pair directly in fragment layout (kstep == slice)
    __hip_atomic_store(hfrag + ((size_t)(t + 1) * 4 + bg) * 4096 +
                           slice * 256 + lane_f * 4 + (uj2 & 3),
                       packh(h0, h1), __ATOMIC_RELAXED, __HIP_MEMORY_SCOPE_AGENT);
    // drains vmcnt(0) in every wave -> all h stores ACKed at L3; also
    // separates this iter's gl reads from next iter's gl writes
    __syncthreads();
    if (tid == 0)
      __hip_atomic_store(fl + slice, (uint32_t)(t + 1),
                         __ATOMIC_RELAXED, __HIP_MEMORY_SCOPE_AGENT);
  }
}

// One WG per (t,b): u[s] = sum_w vt[w]*tanh(blend1[s,b,w]+blend2[t,b,w]),
// then log_softmax over s, write out[b][t][s].
__global__ __launch_bounds__(256) void attn_kernel(const bf16_t* __restrict__ blend1,
                                                   const float* __restrict__ blend2,
                                                   const float* __restrict__ vt_w,
                                                   float* __restrict__ out) {
  __shared__ float s_vt[272], s_b2[272], s_u[512], s_red[8];
  int t = blockIdx.x >> 6;
  int b = blockIdx.x & 63;
  int tid = threadIdx.x, lane = tid & 63, wv = tid >> 6;
  {
    int ww = tid;
    int pi = ww + ((ww >> 6) << 2);
    s_vt[pi] = vt_w[ww];
    s_b2[pi] = blend2[(size_t)(t * 64 + b) * NW + ww];
  }
  __syncthreads();
  int wgrp = lane >> 4, sgrp = lane & 15;
  int base = wgrp * 68;
  for (int it = 0; it < 8; ++it) {
    int s = it * 64 + wv * 16 + sgrp;
    const bf16_t* row = blend1 + ((size_t)s * NB + b) * NW + wgrp * 64;
    float val = 0.f;
#pragma unroll
    for (int c8 = 0; c8 < 8; ++c8) {
      bf16x8 v = *(const bf16x8*)(row + c8 * 8);
#pragma unroll
      for (int jx = 0; jx < 8; ++jx) {
        int wi = base + c8 * 8 + jx;
        val += s_vt[wi] * tanh_f((float)v[jx] + s_b2[wi]);
      }
    }
    val += __shfl_xor(val, 16, 64);
    val += __shfl_xor(val, 32, 64);
    if (wgrp == 0) s_u[it * 64 + wv * 16 + sgrp] = val;
  }
  __syncthreads();
  float a = s_u[tid], bb2 = s_u[tid + 256];
  float m = fmaxf(a, bb2);
#pragma unroll
  for (int off = 1; off < 64; off <<= 1) m = fmaxf(m, __shfl_xor(m, off, 64));
  if (lane == 0) s_red[wv] = m;
  __syncthreads();
  m = fmaxf(fmaxf(s_red[0], s_red[1]), fmaxf(s_red[2], s_red[3]));
  float e = __expf(a - m) + __expf(bb2 - m);
#pragma unroll
  for (int off = 1; off < 64; off <<= 1) e += __shfl_xor(e, off, 64);
  if (lane == 0) s_red[4 + wv] = e;
  __syncthreads();
  float lz = m + logf(s_red[4] + s_red[5] + s_red[6] + s_red[7]);
  size_t ob = ((size_t)b * NTD + t) * NS;
  out[ob + tid] = a - lz;
  out[ob + tid + 256] = bb2 - lz;
}

extern "C" void kernel_launch(void* const* d_in, const int* in_sizes, int n_in,
                              void* d_out, int out_size, void* d_ws, size_t ws_size,
                              hipStream_t stream) {
  const int*   tokens    = (const int*)d_in[0];
  const float* dec_h0    = (const float*)d_in[1];
  const float* emb_table = (const float*)d_in[2];
  const float* enc_Wih   = (const float*)d_in[3];
  const float* enc_Whh   = (const float*)d_in[4];
  const float* enc_bih   = (const float*)d_in[5];
  const float* enc_bhh   = (const float*)d_in[6];
  // d_in[7] = dec_Wih: unused (decoder input is the zero vector)
  const float* dec_Whh   = (const float*)d_in[8];
  const float* dec_bih   = (const float*)d_in[9];
  const float* dec_bhh   = (const float*)d_in[10];
  const float* W1_w      = (const float*)d_in[11];
  const float* W1_b      = (const float*)d_in[12];
  const float* W2_w      = (const float*)d_in[13];
  const float* W2_b      = (const float*)d_in[14];
  const float* vt_w      = (const float*)d_in[15];
  // d_in[16] = vt_b: constant shift, invariant under log_softmax
  float* out = (float*)d_out;

  char* w = (char*)d_ws;
  size_t off = 0;
  auto alloc = [&](size_t bytes) {
    size_t o = off;
    off += (bytes + 255) & ~(size_t)255;
    return o;
  };
  bf16_t* embfrag = (bf16_t*)(w + alloc((size_t)NS * NB * NE * 2));          // 16.8 MB
  bf16_t* xih     = (bf16_t*)(w + alloc((size_t)NS * NB * NG * 2));          // 134 MB
  uint32_t* enc_hf = (uint32_t*)(w + alloc((size_t)(NS + 1) * HSTEP_DW * 4)); // 33.6 MB
  uint32_t* dec_hf = (uint32_t*)(w + alloc((size_t)(NTD + 1) * HSTEP_DW * 4)); // 8.5 MB
  bf16_t* blend1  = (bf16_t*)(w + alloc((size_t)NS * NB * NW * 2));          // 16.8 MB
  float*  blend2  = (float*)(w + alloc((size_t)NTD * NB * NW * 4));          // 8.4 MB
  bf16_t* pWih    = (bf16_t*)(w + alloc((size_t)NG * NE * 2));
  bf16_t* pWhhE   = (bf16_t*)(w + alloc((size_t)NG * NH * 2));
  bf16_t* pWhhD   = (bf16_t*)(w + alloc((size_t)NG * NH * 2));
  bf16_t* pW1     = (bf16_t*)(w + alloc((size_t)NW * NH * 2));
  bf16_t* pW2     = (bf16_t*)(w + alloc((size_t)NW * NH * 2));
  uint32_t* flags = (uint32_t*)(w + alloc(512));
  (void)ws_size; (void)in_sizes; (void)n_in; (void)out_size;

  // per-call init: flags, encoder h0 = 0 (step-0 fragment block)
  hipMemsetAsync(flags, 0, 512, stream);
  hipMemsetAsync(enc_hf, 0, HSTEP_DW * 4, stream);

  // weight packing
  pack_b<<<(NG * NE) / 256, 256, 0, stream>>>(enc_Wih, pWih, NG, NE);
  pack_b<<<(NG * NH) / 256, 256, 0, stream>>>(enc_Whh, pWhhE, NG, NH);
  pack_b<<<(NG * NH) / 256, 256, 0, stream>>>(dec_Whh, pWhhD, NG, NH);
  pack_b<<<(NW * NH) / 256, 256, 0, stream>>>(W1_w, pW1, NW, NH);
  pack_b<<<(NW * NH) / 256, 256, 0, stream>>>(W2_w, pW2, NW, NH);

  // embedding gather (fragment layout), decoder h0 pack
  gather_emb<<<(NS * NB * (NE / 8)) / 256, 256, 0, stream>>>(tokens, emb_table, embfrag);
  pack_h0<<<64, 256, 0, stream>>>(dec_h0, dec_hf);

  // Xih = emb @ Wih.T + bih + bhh  (hoisted; row layout bf16)
  // M = 32768 rows -> 2048 m-tiles, N = 2048 -> 128 n-tiles, K = 256 -> KS 8
  gemm_fa2<bf16_t, 8, 16><<<dim3(128 / 4, 2048 / 16), 256, 0, stream>>>(
      embfrag, pWih, xih, enc_bih, enc_bhh, NG);

  // encoder chain (persistent, 512 steps)
  lstm_chain<true><<<64, 256, 0, stream>>>(pWhhE, xih, nullptr, nullptr,
                                           enc_hf, nullptr, flags, NS);

  // blend1 = enc_states @ W1.T + W1_b (A = enc fragments, skip step 0)
  gemm_fa2<bf16_t, 16, 16><<<dim3(16 / 4, 2048 / 16), 256, 0, stream>>>(
      (const bf16_t*)(enc_hf + HSTEP_DW), pW1, blend1, W1_b, nullptr, NW);

  // decoder chain (128 steps); c0 = last encoder h (fragment block 512)
  lstm_chain<false><<<64, 256, 0, stream>>>(pWhhD, nullptr, dec_bih, dec_bhh,
                                            dec_hf, enc_hf + (size_t)NS * HSTEP_DW,
                                            flags + 64, NTD);

  // blend2 = dec_h @ W2.T + W2_b (fp32, A = dec fragments, skip step 0)
  gemm_fa2<float, 16, 16><<<dim3(16 / 4, 512 / 16), 256, 0, stream>>>(
      (const bf16_t*)(dec_hf + HSTEP_DW), pW2, blend2, W2_b, nullptr, NW);

  // attention + log_softmax -> out [B,T,S]
  attn_kernel<<<NTD * NB, 256, 0, stream>>>(blend1, blend2, vt_w, out);
}